// Round 11
// baseline (149.934 us; speedup 1.0000x reference)
//
#include <hip/hip_runtime.h>
#include <math.h>

// DigitCaps dynamic routing, MI355X. Round 10: 128-route chunks (8 KB) for
// occupancy; W-only pre-pack; DMA staging.
// u[B=128, R=864, I=4] f32, W[1, J=166, R=864, O=8, I=4] f32 -> v[128,166,8] f32.
//
// Round-9 post-mortem: DMA staging fine (no spill, 0 conflicts) but only ~2.3
// waves/SIMD effective (Occupancy 29%) -> latency exposed. Round 10 shrinks
// LDS to 2 x 8 KB chunks (LDS cap 10 blocks/CU; VGPR ~6 blocks/CU = 24
// waves/CU) and deletes the u'-pack (u read f32 in COMPUTE; pre-kernel packs
// W only: W'[j][o][r] fp16-pair uint2, 9.2 MB ws).
// Main kernel: block = 4 waves, one j, 4 consecutive b. 7 chunks of 128
// routes (last masked to 96), double-buffered global_load_lds (16 B/lane,
// lane-order-contiguous LDS), one barrier per chunk. u_hat packed fp16 in
// uint32 regs, constant indices via literal-macro expansion (round-4 spill
// lesson). Routing: b_r = <u_hat, V> via v_dot2_f32_f16, V = running sum of
// v's, no softmax max-pass (shift-invariant, |b_r| small, fp32 exp).

#define BB 128
#define JJ 166
#define RR 864
#define OO 8
#define KMAX 14            // ceil(864/64); k=13 has only lanes 0..31 valid
#define CH_U2 1024         // uint2 per chunk: 128 routes * 8 o

typedef __fp16 h2v __attribute__((ext_vector_type(2)));

__device__ __forceinline__ uint32_t pack2(float a, float b) {
    return __builtin_bit_cast(uint32_t, __builtin_amdgcn_cvt_pkrtz(a, b));
}
__device__ __forceinline__ h2v bc_h2(uint32_t u) {
    return __builtin_bit_cast(h2v, u);
}
__device__ __forceinline__ float lo_f(uint32_t u) {
    return (float)__builtin_bit_cast(h2v, u).x;
}
__device__ __forceinline__ float hi_f(uint32_t u) {
    return (float)__builtin_bit_cast(h2v, u).y;
}

__device__ __forceinline__ float wave_sum(float v) {
#pragma unroll
    for (int m = 32; m >= 1; m >>= 1) v += __shfl_xor(v, m, 64);
    return v;
}

// ---- pre-kernel: W [J][R][O][I] f32 -> W'[j][o][r] fp16-pair uint2 ----
#define WBLOCKS 4482   // J*R*O/256
__global__ __launch_bounds__(256) void pack_kernel(
    const float4* __restrict__ W4, uint2* __restrict__ Wp) {
    const int t = blockIdx.x * 256 + threadIdx.x;  // < J*R*O
    const float4 w = W4[t];
    const int o = t & 7;
    const int jr = t >> 3;
    const int r = jr % RR;
    const int j = jr / RR;
    Wp[(j * OO + o) * RR + r] = make_uint2(pack2(w.x, w.y), pack2(w.z, w.w));
}

__global__ __launch_bounds__(256) void digitcaps_kernel(
    const uint2* __restrict__ Wp, const float* __restrict__ u,
    float* __restrict__ out) {
    const int tid = threadIdx.x;
    const int lane = tid & 63;
    const int wave = tid >> 6;

    // 32 blocks per j; consecutive blocks share j for L2 locality.
    const int j = blockIdx.x >> 5;
    const int b = ((blockIdx.x & 31) << 2) + wave;

    const float4* __restrict__ u4 = (const float4*)u;  // [B][R]

    // two chunk buffers, [o][rl] rows of 128 uint2, lane-order contiguous
    __shared__ uint2 wlds[2][CH_U2];  // 2 x 8,192 B = 16,384 B

    uint32_t uh[KMAX][4];  // u_hat packed fp16 pairs; constant-indexed only

    // ---- DMA chunk CC (rows [o][CC*128 + rl]) into LDS buffer BUF ----
    // Iteration n (n=0,1): 256 threads x 16 B = 512 uint2. lin2 = n*512+tid*2;
    // o = lin2>>7, rl = lin2&127. LDS dest (wave-uniform) element
    // n*512 + wave*128; HW adds lane*16 B -> +lane*2 == lin2. MASKED (chunk 6):
    // only rl<96 valid; masked lanes skip (garbage never read).
#define STAGE(CC, BUF, MASKED)                                                 \
    {                                                                          \
        const uint2* gch = Wp + j * (OO * RR) + (CC) * 128;                    \
        _Pragma("unroll")                                                      \
        for (int n = 0; n < 2; ++n) {                                          \
            const int lin2 = (n << 9) + (tid << 1);                            \
            const int o = lin2 >> 7;                                           \
            const int rl = lin2 & 127;                                         \
            if (!(MASKED) || rl < 96) {                                        \
                const uint2* gsrc = gch + o * RR + rl;                         \
                uint2* ldst = &wlds[BUF][(n << 9) + (wave << 7)];              \
                __builtin_amdgcn_global_load_lds(                              \
                    (const __attribute__((address_space(1))) uint32_t*)gsrc,   \
                    (__attribute__((address_space(3))) uint32_t*)ldst,         \
                    16, 0, 0);                                                 \
            }                                                                  \
        }                                                                      \
    }

    // ---- compute u_hat k-slots {CC*2, CC*2+1} from LDS buffer BUF ----
#define COMPUTE(CC, BUF, KK)                                                   \
    {                                                                          \
        _Pragma("unroll")                                                      \
        for (int kl = 0; kl < (KK); ++kl) {                                    \
            const int rl = (kl << 6) + lane;                                   \
            const bool valid = ((CC) * 2 + kl < KMAX - 1) || (lane < 32);      \
            const int rloff = valid ? rl : 0;                                  \
            const float4 uu4 = u4[b * RR + (CC) * 128 + rloff];                \
            const uint32_t up0 = pack2(uu4.x, uu4.y);                          \
            const uint32_t up1 = pack2(uu4.z, uu4.w);                          \
            float d[OO];                                                       \
            _Pragma("unroll")                                                  \
            for (int o = 0; o < OO; ++o) {                                     \
                const uint2 ww = wlds[BUF][(o << 7) + rl];                     \
                float t0 = __builtin_amdgcn_fdot2(bc_h2(ww.x), bc_h2(up0),     \
                                                  0.0f, false);                \
                d[o] = __builtin_amdgcn_fdot2(bc_h2(ww.y), bc_h2(up1), t0,     \
                                              false);                          \
            }                                                                  \
            _Pragma("unroll")                                                  \
            for (int o2 = 0; o2 < 4; ++o2)                                     \
                uh[(CC) * 2 + kl][o2] =                                        \
                    valid ? pack2(d[2 * o2], d[2 * o2 + 1]) : 0u;              \
        }                                                                      \
    }

    STAGE(0, 0, false)
    __syncthreads();           // drains chunk-0 DMA
    STAGE(1, 1, false)         // chunk-1 loads fly during compute(0)
    COMPUTE(0, 0, 2)
    __syncthreads();
    STAGE(2, 0, false)
    COMPUTE(1, 1, 2)
    __syncthreads();
    STAGE(3, 1, false)
    COMPUTE(2, 0, 2)
    __syncthreads();
    STAGE(4, 0, false)
    COMPUTE(3, 1, 2)
    __syncthreads();
    STAGE(5, 1, false)
    COMPUTE(4, 0, 2)
    __syncthreads();
    STAGE(6, 0, true)
    COMPUTE(5, 1, 2)
    __syncthreads();
    COMPUTE(6, 0, 2)
#undef STAGE
#undef COMPUTE

    float V[OO];  // running sum of past v's (b_r = <uhat_r, V>)
    float v[OO];

    // ---- iteration 0: b=0 -> c uniform = 1/R (packed fp16 partial sums) ----
    {
        h2v accp[4];
#pragma unroll
        for (int o2 = 0; o2 < 4; ++o2) accp[o2] = bc_h2(uh[0][o2]);
#pragma unroll
        for (int k = 1; k < KMAX; ++k)
#pragma unroll
            for (int o2 = 0; o2 < 4; ++o2) accp[o2] += bc_h2(uh[k][o2]);

        float s[OO];
#pragma unroll
        for (int o2 = 0; o2 < 4; ++o2) {
            s[2 * o2]     = wave_sum((float)accp[o2].x) * (1.0f / (float)RR);
            s[2 * o2 + 1] = wave_sum((float)accp[o2].y) * (1.0f / (float)RR);
        }
        float n2 = 0.0f;
#pragma unroll
        for (int o = 0; o < OO; ++o) n2 += s[o] * s[o];
        const float scale = sqrtf(n2) / (1.0f + n2);
#pragma unroll
        for (int o = 0; o < OO; ++o) { v[o] = s[o] * scale; V[o] = v[o]; }
    }

    // ---- iterations 1 and 2 ----
#pragma unroll
    for (int it = 1; it < 3; ++it) {
        uint32_t Vp[4];
#pragma unroll
        for (int o2 = 0; o2 < 4; ++o2)
            Vp[o2] = pack2(V[2 * o2], V[2 * o2 + 1]);

        float zp = 0.0f;
        float sp[OO];
#pragma unroll
        for (int o = 0; o < OO; ++o) sp[o] = 0.0f;

#pragma unroll
        for (int k = 0; k < KMAX; ++k) {
            float br = 0.0f;
#pragma unroll
            for (int o2 = 0; o2 < 4; ++o2)
                br = __builtin_amdgcn_fdot2(bc_h2(uh[k][o2]), bc_h2(Vp[o2]),
                                            br, false);
            // mask invalid routes (k==13, lane>=32): exp(0)=1 would pollute Z
            const float e = (k < KMAX - 1 || lane < 32) ? __expf(br) : 0.0f;
            zp += e;
#pragma unroll
            for (int o2 = 0; o2 < 4; ++o2) {
                sp[2 * o2]     = fmaf(e, lo_f(uh[k][o2]), sp[2 * o2]);
                sp[2 * o2 + 1] = fmaf(e, hi_f(uh[k][o2]), sp[2 * o2 + 1]);
            }
        }
        const float invZ = 1.0f / wave_sum(zp);

        float s[OO];
#pragma unroll
        for (int o = 0; o < OO; ++o) s[o] = wave_sum(sp[o]) * invZ;

        float n2 = 0.0f;
#pragma unroll
        for (int o = 0; o < OO; ++o) n2 += s[o] * s[o];
        const float scale = sqrtf(n2) / (1.0f + n2);
#pragma unroll
        for (int o = 0; o < OO; ++o) v[o] = s[o] * scale;

        if (it < 2) {
#pragma unroll
            for (int o = 0; o < OO; ++o) V[o] += v[o];
        }
    }

    // ---- write out[b][j][o]; v replicated across lanes after butterflies ----
    float outv = 0.0f;
#pragma unroll
    for (int o = 0; o < OO; ++o)
        if (lane == o) outv = v[o];
    if (lane < OO) out[(b * JJ + j) * OO + lane] = outv;
}

extern "C" void kernel_launch(void* const* d_in, const int* in_sizes, int n_in,
                              void* d_out, int out_size, void* d_ws, size_t ws_size,
                              hipStream_t stream) {
    const float* u = (const float*)d_in[0];  // [128, 864, 4]
    const float* W = (const float*)d_in[1];  // [1, 166, 864, 8, 4]
    float* out = (float*)d_out;              // [128, 166, 8]

    uint2* Wp = (uint2*)d_ws;                // 9,179,136 B workspace

    pack_kernel<<<WBLOCKS, 256, 0, stream>>>((const float4*)W, Wp);

    const int grid = JJ * (BB / 4);  // 5312 blocks, 4 waves each
    digitcaps_kernel<<<grid, 256, 0, stream>>>(Wp, u, out);
}

// Round 12
// 149.616 us; speedup vs baseline: 1.0021x; 1.0021x over previous
//
#include <hip/hip_runtime.h>
#include <math.h>

// DigitCaps dynamic routing, MI355X. Round 11: r9 chunking (256 routes, 4
// phases) + whole-u register prefetch + iter-0 sum folded into COMPUTE.
// u[B=128, R=864, I=4] f32, W[1, J=166, R=864, O=8, I=4] f32 -> v[128,166,8] f32.
//
// Evidence so far: barrier count beats LDS footprint (r9 4-phase 88.5us vs
// r10 7-phase 91.5us); OccupancyPercent reads ~40% of cap in every config
// (scaling artifact — not a usable signal); per-k-slot global u loads are the
// largest remaining critical-path latency. Round 11: prefetch all 14 u
// float4s at entry (packed to 14 uint2 = 28 VGPRs) so they complete under
// STAGE(0)'s DMA; COMPUTE is then pure LDS+reg; iteration-0 route-sum
// accumulated in f32 inside COMPUTE while d[] is live.
// Kept: W-only pre-pack to W'[j][o][r] fp16-pair uint2 (9.2 MB ws),
// global_load_lds 16 B DMA staging (lane-order-contiguous LDS, 0 conflicts
// measured), u_hat packed fp16 in uint32 regs with literal-macro constant
// indices (round-4 spill lesson), b_r = <u_hat, V> dot2 routing with running
// V, no softmax max-pass. No launch_bounds (round-6 spill-cliff lesson).

#define BB 128
#define JJ 166
#define RR 864
#define OO 8
#define KMAX 14            // ceil(864/64); k=13 has only lanes 0..31 valid
#define CH_U2 2048         // uint2 per chunk: 256 routes * 8 o

typedef __fp16 h2v __attribute__((ext_vector_type(2)));

__device__ __forceinline__ uint32_t pack2(float a, float b) {
    return __builtin_bit_cast(uint32_t, __builtin_amdgcn_cvt_pkrtz(a, b));
}
__device__ __forceinline__ h2v bc_h2(uint32_t u) {
    return __builtin_bit_cast(h2v, u);
}
__device__ __forceinline__ float lo_f(uint32_t u) {
    return (float)__builtin_bit_cast(h2v, u).x;
}
__device__ __forceinline__ float hi_f(uint32_t u) {
    return (float)__builtin_bit_cast(h2v, u).y;
}

__device__ __forceinline__ float wave_sum(float v) {
#pragma unroll
    for (int m = 32; m >= 1; m >>= 1) v += __shfl_xor(v, m, 64);
    return v;
}

// ---- pre-kernel: W [J][R][O][I] f32 -> W'[j][o][r] fp16-pair uint2 ----
#define WBLOCKS 4482   // J*R*O/256
__global__ __launch_bounds__(256) void pack_kernel(
    const float4* __restrict__ W4, uint2* __restrict__ Wp) {
    const int t = blockIdx.x * 256 + threadIdx.x;  // < J*R*O
    const float4 w = W4[t];
    const int o = t & 7;
    const int jr = t >> 3;
    const int r = jr % RR;
    const int j = jr / RR;
    Wp[(j * OO + o) * RR + r] = make_uint2(pack2(w.x, w.y), pack2(w.z, w.w));
}

__global__ __launch_bounds__(256) void digitcaps_kernel(
    const uint2* __restrict__ Wp, const float* __restrict__ u,
    float* __restrict__ out) {
    const int tid = threadIdx.x;
    const int lane = tid & 63;
    const int wave = tid >> 6;

    // 32 blocks per j; consecutive blocks share j for L2 locality.
    const int j = blockIdx.x >> 5;
    const int b = ((blockIdx.x & 31) << 2) + wave;

    const float4* __restrict__ u4 = (const float4*)u;  // [B][R]

    // two chunk buffers, [o][rl] rows of 256 uint2, lane-order contiguous
    __shared__ uint2 wlds[2][CH_U2];  // 2 x 16,384 B

    uint32_t uh[KMAX][4];  // u_hat packed fp16 pairs; constant-indexed only
    uint2 upk[KMAX];       // prefetched u[b, lane+64k] packed fp16 pairs

    // ---- prefetch ALL u for this (b): 14 independent dwordx4 loads issued
    // up front; they complete while chunk-0's DMA is in flight ----
#pragma unroll
    for (int k = 0; k < KMAX; ++k) {
        const bool valid = (k < KMAX - 1) || (lane < 32);
        const float4 uu = u4[b * RR + (valid ? (k << 6) + lane : 0)];
        upk[k] = make_uint2(pack2(uu.x, uu.y), pack2(uu.z, uu.w));
    }

    float acc[OO];  // iteration-0 per-lane route sums (f32)
#pragma unroll
    for (int o = 0; o < OO; ++o) acc[o] = 0.0f;

    // ---- DMA chunk CC (rows [o][CC*256 + rl]) into LDS buffer BUF ----
    // Iter n: 256 threads x 16 B = 512 uint2. lin2 = n*512 + tid*2;
    // o = lin2>>8 (wave-uniform), rl = lin2&255. LDS dest (wave-uniform)
    // element (n<<9)+(wave<<7); HW adds lane*16 B == lane*2 elements.
    // MASKED (chunk 3): only rl<96 valid; masked lanes skip.
#define STAGE(CC, BUF, MASKED)                                                 \
    {                                                                          \
        const uint2* gch = Wp + j * (OO * RR) + (CC) * 256;                    \
        _Pragma("unroll")                                                      \
        for (int n = 0; n < 4; ++n) {                                          \
            const int lin2 = (n << 9) + (tid << 1);                            \
            const int o = lin2 >> 8;                                           \
            const int rl = lin2 & 255;                                         \
            if (!(MASKED) || rl < 96) {                                        \
                const uint2* gsrc = gch + o * RR + rl;                         \
                uint2* ldst = &wlds[BUF][(n << 9) + (wave << 7)];              \
                __builtin_amdgcn_global_load_lds(                              \
                    (const __attribute__((address_space(1))) uint32_t*)gsrc,   \
                    (__attribute__((address_space(3))) uint32_t*)ldst,         \
                    16, 0, 0);                                                 \
            }                                                                  \
        }                                                                      \
    }

    // ---- compute u_hat k-slots {CC*4..CC*4+KK-1} from LDS buffer BUF ----
#define COMPUTE(CC, BUF, KK)                                                   \
    {                                                                          \
        _Pragma("unroll")                                                      \
        for (int kl = 0; kl < (KK); ++kl) {                                    \
            const int rl = (kl << 6) + lane;                                   \
            const bool valid = ((CC) * 4 + kl < KMAX - 1) || (lane < 32);      \
            const uint2 uu = upk[(CC) * 4 + kl];                               \
            float d[OO];                                                       \
            _Pragma("unroll")                                                  \
            for (int o = 0; o < OO; ++o) {                                     \
                const uint2 ww = wlds[BUF][(o << 8) + rl];                     \
                float t0 = __builtin_amdgcn_fdot2(bc_h2(ww.x), bc_h2(uu.x),    \
                                                  0.0f, false);                \
                d[o] = __builtin_amdgcn_fdot2(bc_h2(ww.y), bc_h2(uu.y), t0,    \
                                              false);                          \
            }                                                                  \
            if (valid) {                                                       \
                _Pragma("unroll")                                              \
                for (int o = 0; o < OO; ++o) acc[o] += d[o];                   \
                _Pragma("unroll")                                              \
                for (int o2 = 0; o2 < 4; ++o2)                                 \
                    uh[(CC) * 4 + kl][o2] = pack2(d[2 * o2], d[2 * o2 + 1]);   \
            } else {                                                           \
                _Pragma("unroll")                                              \
                for (int o2 = 0; o2 < 4; ++o2) uh[(CC) * 4 + kl][o2] = 0u;     \
            }                                                                  \
        }                                                                      \
    }

    STAGE(0, 0, false)
    __syncthreads();           // drains chunk-0 DMA (u prefetch also done)
    STAGE(1, 1, false)         // chunk-1 loads fly during compute(0)
    COMPUTE(0, 0, 4)
    __syncthreads();
    STAGE(2, 0, false)
    COMPUTE(1, 1, 4)
    __syncthreads();
    STAGE(3, 1, true)
    COMPUTE(2, 0, 4)
    __syncthreads();
    COMPUTE(3, 1, 2)
#undef STAGE
#undef COMPUTE

    float V[OO];  // running sum of past v's (b_r = <uhat_r, V>)
    float v[OO];

    // ---- iteration 0: b=0 -> c uniform = 1/R (acc already holds per-lane
    // route sums in f32) ----
    {
        float s[OO];
#pragma unroll
        for (int o = 0; o < OO; ++o)
            s[o] = wave_sum(acc[o]) * (1.0f / (float)RR);

        float n2 = 0.0f;
#pragma unroll
        for (int o = 0; o < OO; ++o) n2 += s[o] * s[o];
        const float scale = sqrtf(n2) / (1.0f + n2);
#pragma unroll
        for (int o = 0; o < OO; ++o) { v[o] = s[o] * scale; V[o] = v[o]; }
    }

    // ---- iterations 1 and 2 ----
#pragma unroll
    for (int it = 1; it < 3; ++it) {
        uint32_t Vp[4];
#pragma unroll
        for (int o2 = 0; o2 < 4; ++o2)
            Vp[o2] = pack2(V[2 * o2], V[2 * o2 + 1]);

        float zp = 0.0f;
        float sp[OO];
#pragma unroll
        for (int o = 0; o < OO; ++o) sp[o] = 0.0f;

#pragma unroll
        for (int k = 0; k < KMAX; ++k) {
            float br = 0.0f;
#pragma unroll
            for (int o2 = 0; o2 < 4; ++o2)
                br = __builtin_amdgcn_fdot2(bc_h2(uh[k][o2]), bc_h2(Vp[o2]),
                                            br, false);
            // mask invalid routes (k==13, lane>=32): exp(0)=1 would pollute Z
            const float e = (k < KMAX - 1 || lane < 32) ? __expf(br) : 0.0f;
            zp += e;
#pragma unroll
            for (int o2 = 0; o2 < 4; ++o2) {
                sp[2 * o2]     = fmaf(e, lo_f(uh[k][o2]), sp[2 * o2]);
                sp[2 * o2 + 1] = fmaf(e, hi_f(uh[k][o2]), sp[2 * o2 + 1]);
            }
        }
        const float invZ = 1.0f / wave_sum(zp);

        float s[OO];
#pragma unroll
        for (int o = 0; o < OO; ++o) s[o] = wave_sum(sp[o]) * invZ;

        float n2 = 0.0f;
#pragma unroll
        for (int o = 0; o < OO; ++o) n2 += s[o] * s[o];
        const float scale = sqrtf(n2) / (1.0f + n2);
#pragma unroll
        for (int o = 0; o < OO; ++o) v[o] = s[o] * scale;

        if (it < 2) {
#pragma unroll
            for (int o = 0; o < OO; ++o) V[o] += v[o];
        }
    }

    // ---- write out[b][j][o]; v replicated across lanes after butterflies ----
    float outv = 0.0f;
#pragma unroll
    for (int o = 0; o < OO; ++o)
        if (lane == o) outv = v[o];
    if (lane < OO) out[(b * JJ + j) * OO + lane] = outv;
}

extern "C" void kernel_launch(void* const* d_in, const int* in_sizes, int n_in,
                              void* d_out, int out_size, void* d_ws, size_t ws_size,
                              hipStream_t stream) {
    const float* u = (const float*)d_in[0];  // [128, 864, 4]
    const float* W = (const float*)d_in[1];  // [1, 166, 864, 8, 4]
    float* out = (float*)d_out;              // [128, 166, 8]

    uint2* Wp = (uint2*)d_ws;                // 9,179,136 B workspace

    pack_kernel<<<WBLOCKS, 256, 0, stream>>>((const float4*)W, Wp);

    const int grid = JJ * (BB / 4);  // 5312 blocks, 4 waves each
    digitcaps_kernel<<<grid, 256, 0, stream>>>(Wp, u, out);
}